// Round 1
// baseline (76.038 us; speedup 1.0000x reference)
//
#include <hip/hip_runtime.h>
#include <stdint.h>

// Binarized MLP: all matmuls are sign(x) @ sign(w)^T => XOR+popcount on
// bit-packed operands. dot = K - 2*popcount(xa ^ xw). Layers 1-3 only feed
// the next binarize, so we only propagate sign bits (packed via __ballot).

#define NB   16384   // batch
#define DIN  784     // input dim
#define HID  512     // hidden dim
#define DOUT 10      // output dim
#define KW1  13      // ceil(784/64)
#define KW2  8       // 512/64
#define RB   32      // batch rows per block in fused kernel

// Pack sign bits of in[rows][K] into u64 words. Word (r,k) covers elements
// [k*64, k*64+64); bit l = (elem < 0). Pad bits = 0 on both operands so they
// never contribute a mismatch. transpose=1 => out[k*rows + r] (for coalesced
// per-column weight loads), else out[r*KW + k].
__global__ void bmlp_pack(const float* __restrict__ in,
                          unsigned long long* __restrict__ out,
                          int rows, int K, int KW, int transpose)
{
    int gw   = (int)((blockIdx.x * blockDim.x + threadIdx.x) >> 6);
    int lane = threadIdx.x & 63;
    if (gw >= rows * KW) return;          // wave-uniform guard
    int r = gw / KW;
    int k = gw - r * KW;
    int e = k * 64 + lane;
    float v = (e < K) ? in[r * K + e] : 1.0f;   // pad -> bit 0
    unsigned long long word = __ballot(v < 0.0f);
    if (lane == 0) {
        if (transpose) out[k * rows + r] = word;
        else           out[r * KW  + k] = word;
    }
}

// One binarized linear + BN + hardtanh + binarize layer.
// actIn: LDS [RB][KW] packed rows. actOut: LDS [RB][KW2] packed sign bits.
// Thread j = output column j (512 threads). Wave wv ballots word wv.
template<int KW>
__device__ __forceinline__ void bin_layer(
    const unsigned long long* actIn,
    unsigned long long* actOut,
    const unsigned long long* __restrict__ WT,   // [KW][HID] transposed-packed
    const float* __restrict__ b, const float* __restrict__ g,
    const float* __restrict__ be, const float* __restrict__ m,
    const float* __restrict__ v, float eps, int K)
{
    int j    = threadIdx.x;
    int wv   = j >> 6;
    int lane = j & 63;

    unsigned long long w[KW];
#pragma unroll
    for (int k = 0; k < KW; ++k) w[k] = WT[k * HID + j];   // lane-coalesced

    float bj = b[j], mj = m[j], bej = be[j];
    // A = g * rsqrt(v+eps), IEEE ops (no fast-math, no contraction)
    float A = __fmul_rn(g[j], __fdiv_rn(1.0f, __fsqrt_rn(__fadd_rn(v[j], eps))));

#pragma unroll 4
    for (int r = 0; r < RB; ++r) {
        int mm = 0;
#pragma unroll
        for (int k = 0; k < KW; ++k)
            mm += (int)__popcll(actIn[r * KW + k] ^ w[k]);  // LDS broadcast read
        float dotf = (float)(K - 2 * mm);                   // exact integer
        float xlin = __fadd_rn(dotf, bj);
        // BN in reference op order: ((x - m) * A) + be ; hardtanh preserves sign
        float y = __fadd_rn(__fmul_rn(__fsub_rn(xlin, mj), A), bej);
        unsigned long long word = __ballot(y < 0.0f);       // bit=1 <=> -1
        if (lane == 0) actOut[r * KW2 + wv] = word;
    }
}

__global__ __launch_bounds__(512)
void bmlp_fused(const unsigned long long* __restrict__ Xp,   // [NB][KW1]
                const unsigned long long* __restrict__ W1T,  // [KW1][HID]
                const unsigned long long* __restrict__ W2T,  // [KW2][HID]
                const unsigned long long* __restrict__ W3T,  // [KW2][HID]
                const unsigned long long* __restrict__ W4p,  // [DOUT][KW2]
                const float* __restrict__ b1, const float* __restrict__ g1,
                const float* __restrict__ be1, const float* __restrict__ m1,
                const float* __restrict__ v1,
                const float* __restrict__ b2, const float* __restrict__ g2,
                const float* __restrict__ be2, const float* __restrict__ m2,
                const float* __restrict__ v2,
                const float* __restrict__ b3, const float* __restrict__ g3,
                const float* __restrict__ be3, const float* __restrict__ m3,
                const float* __restrict__ v3,
                const float* __restrict__ b4,
                float* __restrict__ out)
{
    __shared__ unsigned long long Abuf[RB * KW1];
    __shared__ unsigned long long Bbuf[RB * KW2];
    int row0 = blockIdx.x * RB;

    // stage packed activation rows (coalesced)
    for (int t = threadIdx.x; t < RB * KW1; t += 512)
        Abuf[t] = Xp[row0 * KW1 + t];
    __syncthreads();

    bin_layer<KW1>(Abuf, Bbuf, W1T, b1, g1, be1, m1, v1, 1e-5f, DIN);
    __syncthreads();
    bin_layer<KW2>(Bbuf, Abuf, W2T, b2, g2, be2, m2, v2, 1e-5f, HID);
    __syncthreads();
    bin_layer<KW2>(Abuf, Bbuf, W3T, b3, g3, be3, m3, v3, 512.0f, HID); // EPS3 bug: 512
    __syncthreads();

    // layer 4: out = dot + b4 (fp32), RB*16 == 512 => one task per thread
    {
        int t = threadIdx.x;
        int r = t >> 4, jj = t & 15;
        if (jj < DOUT) {
            int mm = 0;
#pragma unroll
            for (int k = 0; k < KW2; ++k)
                mm += (int)__popcll(Bbuf[r * KW2 + k] ^ W4p[jj * KW2 + k]);
            out[(row0 + r) * DOUT + jj] = __fadd_rn((float)(HID - 2 * mm), b4[jj]);
        }
    }
}

extern "C" void kernel_launch(void* const* d_in, const int* in_sizes, int n_in,
                              void* d_out, int out_size, void* d_ws, size_t ws_size,
                              hipStream_t stream)
{
    const float* x   = (const float*)d_in[0];
    const float* w1  = (const float*)d_in[1];
    const float* b1  = (const float*)d_in[2];
    const float* g1  = (const float*)d_in[3];
    const float* be1 = (const float*)d_in[4];
    const float* m1  = (const float*)d_in[5];
    const float* v1  = (const float*)d_in[6];
    const float* w2  = (const float*)d_in[7];
    const float* b2  = (const float*)d_in[8];
    const float* g2  = (const float*)d_in[9];
    const float* be2 = (const float*)d_in[10];
    const float* m2  = (const float*)d_in[11];
    const float* v2  = (const float*)d_in[12];
    const float* w3  = (const float*)d_in[13];
    const float* b3  = (const float*)d_in[14];
    const float* g3  = (const float*)d_in[15];
    const float* be3 = (const float*)d_in[16];
    const float* m3  = (const float*)d_in[17];
    const float* v3  = (const float*)d_in[18];
    const float* w4  = (const float*)d_in[19];
    const float* b4  = (const float*)d_in[20];
    float* out = (float*)d_out;

    // workspace layout (u64, all 8B-aligned): ~1.82 MB total
    unsigned long long* Xp  = (unsigned long long*)d_ws;
    unsigned long long* W1T = Xp  + (size_t)NB  * KW1;
    unsigned long long* W2T = W1T + (size_t)KW1 * HID;
    unsigned long long* W3T = W2T + (size_t)KW2 * HID;
    unsigned long long* W4p = W3T + (size_t)KW2 * HID;

    // pack x and weights
    bmlp_pack<<<dim3((NB  * KW1 * 64 + 255) / 256), 256, 0, stream>>>(x,  Xp,  NB,  DIN, KW1, 0);
    bmlp_pack<<<dim3((HID * KW1 * 64 + 255) / 256), 256, 0, stream>>>(w1, W1T, HID, DIN, KW1, 1);
    bmlp_pack<<<dim3((HID * KW2 * 64 + 255) / 256), 256, 0, stream>>>(w2, W2T, HID, HID, KW2, 1);
    bmlp_pack<<<dim3((HID * KW2 * 64 + 255) / 256), 256, 0, stream>>>(w3, W3T, HID, HID, KW2, 1);
    bmlp_pack<<<dim3((DOUT* KW2 * 64 + 255) / 256), 256, 0, stream>>>(w4, W4p, DOUT, HID, KW2, 0);

    // fused 4-layer MLP
    bmlp_fused<<<dim3(NB / RB), 512, 0, stream>>>(
        Xp, W1T, W2T, W3T, W4p,
        b1, g1, be1, m1, v1,
        b2, g2, be2, m2, v2,
        b3, g3, be3, m3, v3,
        b4, out);
}